// Round 6
// baseline (46.061 us; speedup 1.0000x reference)
//
#include <hip/hip_runtime.h>
#include <hip/hip_bf16.h>

#define NB 384
#define ND 512

// ---------------- Kernel 1: scores = emb @ emb.T (f32), split-K=2 ----------
__global__ __launch_bounds__(256) void gemm_scores(const float* __restrict__ emb,
                                                   float* __restrict__ s0,
                                                   float* __restrict__ s1) {
    __shared__ float As[32][65];
    __shared__ float Bs[32][65];
    const int tid = threadIdx.x;
    const int tx = tid & 15, ty = tid >> 4;
    const int i0 = blockIdx.y * 32, j0 = blockIdx.x * 32;
    const int kbase = blockIdx.z * (ND / 2);
    float* __restrict__ s = blockIdx.z ? s1 : s0;
    float acc00 = 0.f, acc01 = 0.f, acc10 = 0.f, acc11 = 0.f;

    for (int k0 = kbase; k0 < kbase + ND / 2; k0 += 64) {
#pragma unroll
        for (int p = 0; p < 2; ++p) {
            int idx = tid + 256 * p;
            int r = idx >> 4;
            int c = (idx & 15) << 2;
            float4 av = *reinterpret_cast<const float4*>(emb + (i0 + r) * ND + k0 + c);
            As[r][c] = av.x; As[r][c + 1] = av.y; As[r][c + 2] = av.z; As[r][c + 3] = av.w;
            float4 bv = *reinterpret_cast<const float4*>(emb + (j0 + r) * ND + k0 + c);
            Bs[r][c] = bv.x; Bs[r][c + 1] = bv.y; Bs[r][c + 2] = bv.z; Bs[r][c + 3] = bv.w;
        }
        __syncthreads();
#pragma unroll 8
        for (int kk = 0; kk < 64; ++kk) {
            float a0 = As[2 * ty][kk], a1 = As[2 * ty + 1][kk];
            float b0 = Bs[2 * tx][kk], b1 = Bs[2 * tx + 1][kk];
            acc00 = fmaf(a0, b0, acc00); acc01 = fmaf(a0, b1, acc01);
            acc10 = fmaf(a1, b0, acc10); acc11 = fmaf(a1, b1, acc11);
        }
        __syncthreads();
    }
    const int i = i0 + 2 * ty, j = j0 + 2 * tx;
    s[i * NB + j]           = acc00; s[i * NB + j + 1]       = acc01;
    s[(i + 1) * NB + j]     = acc10; s[(i + 1) * NB + j + 1] = acc11;
}

// ---------------- Kernel 2: prep — sum K-halves, group scores by t-class ---
// One block per b, 384 threads. Exact permutation; j-sums are order-free.
__global__ __launch_bounds__(NB) void hap_prep(const float* __restrict__ s0,
                                               const float* __restrict__ s1,
                                               const int* __restrict__ labels,
                                               float* __restrict__ g,
                                               int* __restrict__ offs,
                                               float* __restrict__ tsumArr) {
    __shared__ int wcnt[6][4];
    __shared__ int wbase[6][4];
    __shared__ int cbase[4];
    const int tid = threadIdx.x, lane = tid & 63, wv = tid >> 6;
    const int b = blockIdx.x;
    const int l0 = labels[b * 3 + 0], l1 = labels[b * 3 + 1], l2 = labels[b * 3 + 2];
    const int t = (labels[tid * 3 + 0] == l0) + (labels[tid * 3 + 1] == l1) +
                  (labels[tid * 3 + 2] == l2);
    const float sv = s0[b * NB + tid] + s1[b * NB + tid];
    const unsigned long long mlt = (1ull << lane) - 1ull;
    int myrank = 0;
#pragma unroll
    for (int c = 0; c < 4; ++c) {
        unsigned long long m = __ballot(t == c);
        if (t == c) myrank = __popcll(m & mlt);
        if (lane == 0) wcnt[wv][c] = __popcll(m);
    }
    __syncthreads();
    if (tid == 0) {
        int tot0 = 0, tot1 = 0, tot2 = 0, tot3 = 0;
        for (int w = 0; w < 6; ++w) {
            wbase[w][0] = tot0; tot0 += wcnt[w][0];
            wbase[w][1] = tot1; tot1 += wcnt[w][1];
            wbase[w][2] = tot2; tot2 += wcnt[w][2];
            wbase[w][3] = tot3; tot3 += wcnt[w][3];
        }
        cbase[0] = 0; cbase[1] = tot0; cbase[2] = tot0 + tot1; cbase[3] = tot0 + tot1 + tot2;
        offs[b * 4 + 0] = cbase[1];
        offs[b * 4 + 1] = cbase[2];
        offs[b * 4 + 2] = cbase[3];
        tsumArr[b] = (float)(tot1 + 2 * tot2 + 3 * tot3);
    }
    __syncthreads();
    g[b * NB + cbase[t] + wbase[wv][t] + myrank] = sv;
}

// ---------------- Kernel 3: partial rank/hrank over a 96-j quarter --------
// grid (384, 2, 4) = (b, ihalf, jquarter); 192 threads; one thread per row i.
// Grouped positions: [0, R[ti]) = inferior (sigmoid), [R[ti], NB) = count.
// Per-quarter boundary m = clamp(R[ti]-q0, 0, 96); branch is wave-uniform
// except at class-boundary waves. Diagonal falls in the count region (+1, +ti).
__global__ __launch_bounds__(192) void hap_part(const float* __restrict__ g,
                                                const int* __restrict__ offs,
                                                float2* __restrict__ part) {
    __shared__ alignas(16) float gs[96];
    const int tid = threadIdx.x;
    const int b = blockIdx.x, ih = blockIdx.y, jh = blockIdx.z;
    const int q0 = jh * 96;

    if (tid < 96) gs[tid] = g[b * NB + q0 + tid];
    const int i = ih * 192 + tid;
    const float si = g[b * NB + i];
    const int S1 = offs[b * 4 + 0], S2 = offs[b * 4 + 1], S3 = offs[b * 4 + 2];
    const int ti = (i >= S1) + (i >= S2) + (i >= S3);
    __syncthreads();

    const int Rti = (ti == 0) ? 0 : (ti == 1) ? S1 : (ti == 2) ? S2 : S3;
    int m = Rti - q0; m = m < 0 ? 0 : (m > 96 ? 96 : m);

    const float nsiK = si * 144.26950408889634f;
    const float pconst = fmaf(-100.f, si, -3.56f);   // ramp = 100*sj + pconst
    const float c1 = si + 0.05f;

    float rs = 0.f, hs = 0.f;
    int k = 0;
#pragma unroll 4
    for (; k < m; ++k) {
        const float sj = gs[k];
        const float ex = __builtin_amdgcn_exp2f(fmaf(sj, -144.26950408889634f, nsiK));
        const float sg = __builtin_amdgcn_rcpf(1.f + ex);
        const float posb = fmaf(100.f, sj, pconst);
        const float sel = (sj > c1) ? posb : (0.5f + sg);
        rs += (sj > si) ? sel : sg;
        const int pos = q0 + k;
        const float wk = (float)((pos >= S1) + (pos >= S2));  // == class(pos) here
        hs += (sj >= si) ? wk : 0.f;
    }
    int cnt = 0;
#pragma unroll 8
    for (; k < 96; ++k) cnt += (gs[k] >= si) ? 1 : 0;

    rs += (float)cnt;
    hs += (float)(ti * cnt);
    part[(jh * NB + b) * NB + i] = make_float2(rs, hs);
}

// ---------------- Kernel 4: per-b combine ----------------
// mhap_b = sum_i (h_i / r_i) / sum_j t_j     (the /3's cancel)
__global__ __launch_bounds__(192) void hap_combine(const float2* __restrict__ part,
                                                   const float* __restrict__ tsumArr,
                                                   float* __restrict__ bsum) {
    __shared__ float redQ[3];
    const int tid = threadIdx.x, lane = tid & 63, wv = tid >> 6;
    const int b = blockIdx.x;
    float q = 0.f;
#pragma unroll
    for (int rep = 0; rep < 2; ++rep) {
        const int i = rep * 192 + tid;
        float r = 0.f, h = 0.f;
#pragma unroll
        for (int jh = 0; jh < 4; ++jh) {
            const float2 p = part[(jh * NB + b) * NB + i];
            r += p.x; h += p.y;
        }
        q += h / r;
    }
#pragma unroll
    for (int off = 32; off > 0; off >>= 1) q += __shfl_xor(q, off, 64);
    if (lane == 0) redQ[wv] = q;
    __syncthreads();
    if (tid == 0) bsum[b] = (redQ[0] + redQ[1] + redQ[2]) / (tsumArr[b] * (float)NB);
}

// ---------------- Kernel 5: final reduce ----------------
__global__ __launch_bounds__(64) void hap_final(const float* __restrict__ bsum,
                                                float* __restrict__ out) {
    const int tid = threadIdx.x;
    float p = 0.f;
    for (int k = tid; k < NB; k += 64) p += bsum[k];
#pragma unroll
    for (int off = 32; off > 0; off >>= 1) p += __shfl_xor(p, off, 64);
    if (tid == 0) out[0] = 1.f - p;
}

extern "C" void kernel_launch(void* const* d_in, const int* in_sizes, int n_in,
                              void* d_out, int out_size, void* d_ws, size_t ws_size,
                              hipStream_t stream) {
    const float* emb = (const float*)d_in[0];
    const int* labels = (const int*)d_in[1];
    float* out = (float*)d_out;

    float* s0 = (float*)d_ws;                    // 147456 f32
    float* s1 = s0 + NB * NB;                    // 147456 f32
    float* g  = s1 + NB * NB;                    // 147456 f32 (grouped scores)
    float2* part = (float2*)(g + NB * NB);       // 4 * 147456 float2
    int* offs = (int*)(part + 4 * NB * NB);      // 384*4 int
    float* tsumArr = (float*)(offs + NB * 4);    // 384 f32
    float* bsum = tsumArr + NB;                  // 384 f32

    gemm_scores<<<dim3(12, 12, 2), 256, 0, stream>>>(emb, s0, s1);
    hap_prep<<<NB, NB, 0, stream>>>(s0, s1, labels, g, offs, tsumArr);
    hap_part<<<dim3(NB, 2, 4), 192, 0, stream>>>(g, offs, part);
    hap_combine<<<NB, 192, 0, stream>>>(part, tsumArr, bsum);
    hap_final<<<1, 64, 0, stream>>>(bsum, out);
}

// Round 7
// 38.726 us; speedup vs baseline: 1.1894x; 1.1894x over previous
//
#include <hip/hip_runtime.h>
#include <hip/hip_bf16.h>

#define NB 384
#define ND 512
#define NZ 8   // GEMM split-K factor

// ---------------- Kernel 1: scores partials, 64x64 tile, 4x4/thread -------
// grid (6,6,8): blockIdx.z = K-chunk of 64. LDS stored transposed [k][i] so
// A/B fragments are single ds_read_b128 (2 LDS instrs per 16 FMA).
__global__ __launch_bounds__(256) void gemm_scores(const float* __restrict__ emb,
                                                   float* __restrict__ sp) {
    __shared__ alignas(16) float At[64 * 68];   // [kk][ii], stride 68 (16B-aligned rows)
    __shared__ alignas(16) float Bt[64 * 68];
    const int tid = threadIdx.x;
    const int i0 = blockIdx.y * 64, j0 = blockIdx.x * 64;
    const int kb = blockIdx.z * 64;
    float* __restrict__ s = sp + blockIdx.z * (NB * NB);

#pragma unroll
    for (int p = 0; p < 4; ++p) {
        const int idx = tid + 256 * p;
        const int r = idx >> 4;             // 0..63
        const int c4 = (idx & 15) << 2;     // 0..60
        const float4 av = *reinterpret_cast<const float4*>(emb + (i0 + r) * ND + kb + c4);
        At[(c4 + 0) * 68 + r] = av.x;
        At[(c4 + 1) * 68 + r] = av.y;
        At[(c4 + 2) * 68 + r] = av.z;
        At[(c4 + 3) * 68 + r] = av.w;
        const float4 bv = *reinterpret_cast<const float4*>(emb + (j0 + r) * ND + kb + c4);
        Bt[(c4 + 0) * 68 + r] = bv.x;
        Bt[(c4 + 1) * 68 + r] = bv.y;
        Bt[(c4 + 2) * 68 + r] = bv.z;
        Bt[(c4 + 3) * 68 + r] = bv.w;
    }
    __syncthreads();

    const int tx = tid & 15, ty = tid >> 4;
    float acc[4][4] = {};
#pragma unroll 4
    for (int kk = 0; kk < 64; ++kk) {
        const float4 a = *reinterpret_cast<const float4*>(&At[kk * 68 + ty * 4]);
        const float4 b = *reinterpret_cast<const float4*>(&Bt[kk * 68 + tx * 4]);
        acc[0][0] = fmaf(a.x, b.x, acc[0][0]); acc[0][1] = fmaf(a.x, b.y, acc[0][1]);
        acc[0][2] = fmaf(a.x, b.z, acc[0][2]); acc[0][3] = fmaf(a.x, b.w, acc[0][3]);
        acc[1][0] = fmaf(a.y, b.x, acc[1][0]); acc[1][1] = fmaf(a.y, b.y, acc[1][1]);
        acc[1][2] = fmaf(a.y, b.z, acc[1][2]); acc[1][3] = fmaf(a.y, b.w, acc[1][3]);
        acc[2][0] = fmaf(a.z, b.x, acc[2][0]); acc[2][1] = fmaf(a.z, b.y, acc[2][1]);
        acc[2][2] = fmaf(a.z, b.z, acc[2][2]); acc[2][3] = fmaf(a.z, b.w, acc[2][3]);
        acc[3][0] = fmaf(a.w, b.x, acc[3][0]); acc[3][1] = fmaf(a.w, b.y, acc[3][1]);
        acc[3][2] = fmaf(a.w, b.z, acc[3][2]); acc[3][3] = fmaf(a.w, b.w, acc[3][3]);
    }
#pragma unroll
    for (int u = 0; u < 4; ++u) {
        float4 o = make_float4(acc[u][0], acc[u][1], acc[u][2], acc[u][3]);
        *reinterpret_cast<float4*>(&s[(i0 + ty * 4 + u) * NB + j0 + tx * 4]) = o;
    }
}

// ---------------- Kernel 2: fused group + rank/hrank + reduce -------------
// grid (384, 4) = (b, i-quarter); 384 threads (6 waves).
// Lane-quad: it = tid>>2 (row i), jt = tid&3 (j-slice). 16 consecutive i's
// per wave -> ti wave-uniform (except class-boundary waves).
// Sigmoid region [0,Rti): strided-by-4 scalar (balanced, broadcast reads).
// Count region [Rti,384): float4 reads strided by quad (4 elems/ds_read).
// Diagonal is implicit: falls in count region (+1 rank, +ti hsum).
__global__ __launch_bounds__(384) void hap_fused(const float* __restrict__ sp,
                                                 const int* __restrict__ labels,
                                                 float* __restrict__ bpart) {
    __shared__ alignas(16) float gs[NB];
    __shared__ int wcnt[6][4];
    __shared__ int wbase[6][4];
    __shared__ int cb[4];
    __shared__ float tsum_sh;
    __shared__ float redQ[6];

    const int tid = threadIdx.x, lane = tid & 63, wv = tid >> 6;
    const int b = blockIdx.x, iq = blockIdx.y;

    const int l0 = labels[b * 3 + 0], l1 = labels[b * 3 + 1], l2 = labels[b * 3 + 2];
    const int t = (labels[tid * 3 + 0] == l0) + (labels[tid * 3 + 1] == l1) +
                  (labels[tid * 3 + 2] == l2);
    float sv = 0.f;
#pragma unroll
    for (int z = 0; z < NZ; ++z) sv += sp[z * NB * NB + b * NB + tid];

    const unsigned long long mlt = (1ull << lane) - 1ull;
    int rk = 0;
#pragma unroll
    for (int c = 0; c < 4; ++c) {
        unsigned long long m = __ballot(t == c);
        if (t == c) rk = __popcll(m & mlt);
        if (lane == 0) wcnt[wv][c] = __popcll(m);
    }
    __syncthreads();
    if (tid == 0) {
        int tot0 = 0, tot1 = 0, tot2 = 0, tot3 = 0;
        for (int w = 0; w < 6; ++w) {
            wbase[w][0] = tot0; tot0 += wcnt[w][0];
            wbase[w][1] = tot1; tot1 += wcnt[w][1];
            wbase[w][2] = tot2; tot2 += wcnt[w][2];
            wbase[w][3] = tot3; tot3 += wcnt[w][3];
        }
        cb[0] = 0; cb[1] = tot0; cb[2] = tot0 + tot1; cb[3] = tot0 + tot1 + tot2;
        tsum_sh = (float)(tot1 + 2 * tot2 + 3 * tot3);
    }
    __syncthreads();
    gs[cb[t] + wbase[wv][t] + rk] = sv;
    __syncthreads();

    const int S1 = cb[1], S2 = cb[2], S3 = cb[3];
    const int it = tid >> 2, jt = tid & 3;
    const int i = iq * 96 + it;
    const float si = gs[i];
    const int ti = (i >= S1) + (i >= S2) + (i >= S3);
    const int Rti = (ti == 0) ? 0 : (ti == 1) ? S1 : (ti == 2) ? S2 : S3;

    const float siK = si * 144.26950408889634f;
    const float pconst = fmaf(-100.f, si, -3.56f);   // ramp = 100*sj + pconst
    const float c1 = si + 0.05f;

    float rs = 0.f;
    int hsI = 0, cnt = 0;
    // sigmoid region: grouped positions [0, Rti), this lane takes k = jt mod 4
    for (int k = jt; k < Rti; k += 4) {
        const float sj = gs[k];
        const float ex = __builtin_amdgcn_exp2f(fmaf(sj, -144.26950408889634f, siK));
        const float sg = __builtin_amdgcn_rcpf(1.f + ex);
        const float ramp = fmaf(100.f, sj, pconst);
        const float sel = (sj > c1) ? ramp : (0.5f + sg);
        rs += (sj > si) ? sel : sg;
        const int wk = (k >= S1) + (k >= S2);        // == class(k), k < Rti <= S3
        hsI += (sj >= si) ? wk : 0;
    }
    // count region head: [Rti, a0) with a0 = 4-aligned
    const int a0 = (Rti + 3) & ~3;
    if (Rti + jt < a0) cnt += (gs[Rti + jt] >= si) ? 1 : 0;
    // count region vector body: [a0, 384), quad-strided float4
    const float4* gv = reinterpret_cast<const float4*>(gs);
    for (int k4 = (a0 >> 2) + jt; k4 < (NB >> 2); k4 += 4) {
        const float4 v = gv[k4];
        cnt += ((v.x >= si) ? 1 : 0) + ((v.y >= si) ? 1 : 0) +
               ((v.z >= si) ? 1 : 0) + ((v.w >= si) ? 1 : 0);
    }
    rs += (float)cnt;
    hsI += ti * cnt;

    // combine the 4 j-slices within the lane-quad
    rs += __shfl_xor(rs, 1); rs += __shfl_xor(rs, 2);
    float hs = (float)hsI;
    hs += __shfl_xor(hs, 1); hs += __shfl_xor(hs, 2);
    float q = hs / rs;                 // duplicated 4x per i -> scale by 1/4 later
#pragma unroll
    for (int off = 32; off > 0; off >>= 1) q += __shfl_xor(q, off, 64);
    if (lane == 0) redQ[wv] = q;
    __syncthreads();
    if (tid == 0) {
        const float tot = redQ[0] + redQ[1] + redQ[2] + redQ[3] + redQ[4] + redQ[5];
        bpart[b * 4 + iq] = tot / (4.f * tsum_sh * (float)NB);
    }
}

// ---------------- Kernel 3: final reduce over 1536 partials ----------------
__global__ __launch_bounds__(256) void hap_final(const float* __restrict__ bpart,
                                                 float* __restrict__ out) {
    __shared__ float red[4];
    const int tid = threadIdx.x, lane = tid & 63, wv = tid >> 6;
    float p = 0.f;
    for (int k = tid; k < NB * 4; k += 256) p += bpart[k];
#pragma unroll
    for (int off = 32; off > 0; off >>= 1) p += __shfl_xor(p, off, 64);
    if (lane == 0) red[wv] = p;
    __syncthreads();
    if (tid == 0) out[0] = 1.f - (red[0] + red[1] + red[2] + red[3]);
}

extern "C" void kernel_launch(void* const* d_in, const int* in_sizes, int n_in,
                              void* d_out, int out_size, void* d_ws, size_t ws_size,
                              hipStream_t stream) {
    const float* emb = (const float*)d_in[0];
    const int* labels = (const int*)d_in[1];
    float* out = (float*)d_out;

    float* sp = (float*)d_ws;                    // NZ * 147456 f32 partial scores
    float* bpart = sp + NZ * NB * NB;            // 1536 f32

    gemm_scores<<<dim3(6, 6, NZ), 256, 0, stream>>>(emb, sp);
    hap_fused<<<dim3(NB, 4), 384, 0, stream>>>(sp, labels, bpart);
    hap_final<<<1, 256, 0, stream>>>(bpart, out);
}